// Round 3
// baseline (811.090 us; speedup 1.0000x reference)
//
#include <hip/hip_runtime.h>

#define B_ 4
#define C_ 512
#define L_ 4096

typedef __attribute__((ext_vector_type(8))) short bf16x8;
typedef __attribute__((ext_vector_type(4))) float f32x4;

static __device__ __forceinline__ unsigned short f2bf_rne(float f) {
  unsigned u = __float_as_uint(f);
  u += 0x7FFFu + ((u >> 16) & 1u);  // round-to-nearest-even
  return (unsigned short)(u >> 16);
}
static __device__ __forceinline__ unsigned pack_rne(float a, float b) {
  return (unsigned)f2bf_rne(a) | ((unsigned)f2bf_rne(b) << 16);
}
static __device__ __forceinline__ unsigned pack_trunc(float a, float b) {
  return (__float_as_uint(a) >> 16) | (__float_as_uint(b) & 0xFFFF0000u);
}

// async global -> LDS, 16 B/lane; LDS dest = wave-uniform base + lane*16.
static __device__ __forceinline__ void g2lds16(const unsigned short* g,
                                               unsigned short* l) {
  __builtin_amdgcn_global_load_lds(
      (const __attribute__((address_space(1))) unsigned int*)g,
      (__attribute__((address_space(3))) unsigned int*)l, 16, 0, 0);
}

// ---------------------------------------------------------------------------
// K0: Q,K fp32 (C,L) -> Qt,Kt bf16 (L,C).  grid (L/64, C/64, B*2), block 256
// ---------------------------------------------------------------------------
__global__ __launch_bounds__(256) void transpose_cast_k(
    const float* __restrict__ Q, const float* __restrict__ K,
    unsigned short* __restrict__ Qt, unsigned short* __restrict__ Kt) {
  int zb = blockIdx.z;
  int b = zb >> 1;
  const float* src = ((zb & 1) ? K : Q) + (size_t)b * C_ * L_;
  unsigned short* dst = ((zb & 1) ? Kt : Qt) + (size_t)b * L_ * C_;
  int i0 = blockIdx.x * 64, c0 = blockIdx.y * 64;
  __shared__ float tile[64][65];  // pad 65: 2-way bank alias only (free)
  int t = threadIdx.x;
  int cr = t >> 2, ig = (t & 3) * 16;
  const float* s = src + (size_t)(c0 + cr) * L_ + i0 + ig;
#pragma unroll
  for (int q = 0; q < 4; ++q) {
    float4 v = *(const float4*)(s + 4 * q);
    tile[cr][ig + 4 * q + 0] = v.x;
    tile[cr][ig + 4 * q + 1] = v.y;
    tile[cr][ig + 4 * q + 2] = v.z;
    tile[cr][ig + 4 * q + 3] = v.w;
  }
  __syncthreads();
  int ir = t >> 2, cg = (t & 3) * 16;
  unsigned wds[8];
#pragma unroll
  for (int k = 0; k < 8; ++k)
    wds[k] = pack_rne(tile[cg + 2 * k][ir], tile[cg + 2 * k + 1][ir]);
  unsigned short* d = dst + (size_t)(i0 + ir) * C_ + c0 + cg;
  uint4 o0, o1;
  o0.x = wds[0]; o0.y = wds[1]; o0.z = wds[2]; o0.w = wds[3];
  o1.x = wds[4]; o1.y = wds[5]; o1.z = wds[6]; o1.w = wds[7];
  *(uint4*)d = o0;
  *(uint4*)(d + 8) = o1;
}

// ---------------------------------------------------------------------------
// K0b: Vb[b,c,j] = bf16(V[b,c,j] * mask[b,j])   (post-softmax mask folded in)
// grid (B*C*L/2048), block 256, 8 elems/thread
// ---------------------------------------------------------------------------
__global__ __launch_bounds__(256) void cast_v_k(
    const float* __restrict__ V, const float* __restrict__ mask,
    unsigned short* __restrict__ Vb) {
  size_t idx = ((size_t)blockIdx.x * 256 + threadIdx.x) * 8;
  int b = (int)(idx >> 21);        // C*L = 2^21
  int j = (int)(idx & (L_ - 1));
  float4 v0 = *(const float4*)(V + idx);
  float4 v1 = *(const float4*)(V + idx + 4);
  const float* m = mask + (size_t)b * L_ + j;
  float4 m0 = *(const float4*)m;
  float4 m1 = *(const float4*)(m + 4);
  uint4 o;
  o.x = pack_rne(v0.x * m0.x, v0.y * m0.y);
  o.y = pack_rne(v0.z * m0.z, v0.w * m0.w);
  o.z = pack_rne(v1.x * m1.x, v1.y * m1.y);
  o.w = pack_rne(v1.z * m1.z, v1.w * m1.w);
  *(uint4*)(Vb + idx) = o;
}

// ---------------------------------------------------------------------------
// m97-style NT GEMM mainloop (both operands bf16, k-contiguous, async staged):
// C[m,n] += sum_k A[m,k]*B[n,k].  128x128 tile, BK=32, 4 waves of 4x4 MFMA.
// ---------------------------------------------------------------------------
__device__ __forceinline__ void gemm_mainloop(
    const unsigned short* Ab, const unsigned short* Bb, int lda, int ldb,
    int Kdim, unsigned short* sA, unsigned short* sB, f32x4 acc[4][4]) {
  int t = threadIdx.x;
  int f0 = t * 8;
  int f1 = 2048 + t * 8;
  int r0 = f0 >> 5, q0 = f0 & 31;
  int r1 = f1 >> 5, q1 = f1 & 31;
  const unsigned short* pA0 = Ab + (size_t)r0 * lda + q0;
  const unsigned short* pA1 = Ab + (size_t)r1 * lda + q1;
  const unsigned short* pB0 = Bb + (size_t)r0 * ldb + q0;
  const unsigned short* pB1 = Bb + (size_t)r1 * ldb + q1;
  int lane = t & 63;
  int quad = lane >> 4;
  int l15 = lane & 15;
  int w = t >> 6;
  int wm = (w & 1) * 64;
  int wn = (w >> 1) * 64;
  for (int kk = 0; kk < Kdim; kk += 32) {
    __syncthreads();
    g2lds16(pA0 + kk, sA + f0);
    g2lds16(pA1 + kk, sA + f1);
    g2lds16(pB0 + kk, sB + f0);
    g2lds16(pB1 + kk, sB + f1);
    __syncthreads();
    bf16x8 aF[4], bF[4];
#pragma unroll
    for (int ti = 0; ti < 4; ++ti)
      aF[ti] = *(const bf16x8*)(sA + (wm + ti * 16 + l15) * 32 + quad * 8);
#pragma unroll
    for (int tj = 0; tj < 4; ++tj)
      bF[tj] = *(const bf16x8*)(sB + (wn + tj * 16 + l15) * 32 + quad * 8);
#pragma unroll
    for (int ti = 0; ti < 4; ++ti)
#pragma unroll
      for (int tj = 0; tj < 4; ++tj)
        acc[ti][tj] = __builtin_amdgcn_mfma_f32_16x16x32_bf16(
            aF[ti], bF[tj], acc[ti][tj], 0, 0, 0);
  }
}

// ---------------------------------------------------------------------------
// K1: E = Qt*Kt^T; t = exp(E*scale + log(mask_j+1e-6)) -> attn fp32 (i,j),
// fp32 rowsum atomics.  grid (L/128, L/128, B)
// ---------------------------------------------------------------------------
__global__ __launch_bounds__(256) void gemm1_k(
    const unsigned short* __restrict__ Qt, const unsigned short* __restrict__ Kt,
    const float* __restrict__ mask, float* __restrict__ attn,
    float* __restrict__ rowsum) {
  int b = blockIdx.z;
  int i0 = blockIdx.y * 128;
  int j0 = blockIdx.x * 128;
  __shared__ unsigned short sA[128 * 32];
  __shared__ unsigned short sB[128 * 32];
  f32x4 acc[4][4] = {};
  gemm_mainloop(Qt + (size_t)b * L_ * C_ + (size_t)i0 * C_,
                Kt + (size_t)b * L_ * C_ + (size_t)j0 * C_, C_, C_, C_, sA, sB,
                acc);
  int t = threadIdx.x;
  int lane = t & 63;
  int quad = lane >> 4;
  int l15 = lane & 15;
  int w = t >> 6;
  int wm = (w & 1) * 64;
  int wn = (w >> 1) * 64;
  const float scale = 0.04419417382415922f;  // 1/sqrt(512)
  float lm[4];
#pragma unroll
  for (int tj = 0; tj < 4; ++tj) {
    int j = j0 + wn + tj * 16 + l15;
    lm[tj] = __logf(mask[(size_t)b * L_ + j] + 1e-6f);
  }
  float* ab = attn + (size_t)b * L_ * L_;
  float rs[16];
#pragma unroll
  for (int q = 0; q < 16; ++q) rs[q] = 0.f;
#pragma unroll
  for (int ti = 0; ti < 4; ++ti) {
    int irow = i0 + wm + ti * 16 + quad * 4;  // C/D: row = quad*4 + reg
#pragma unroll
    for (int r = 0; r < 4; ++r) {
      size_t ro = (size_t)(irow + r) * L_;
#pragma unroll
      for (int tj = 0; tj < 4; ++tj) {
        float x = fminf(acc[ti][tj][r] * scale + lm[tj], 60.f);
        float tv = __expf(x);  // |logit| small: max-free softmax is safe
        rs[ti * 4 + r] += tv;
        ab[ro + j0 + wn + tj * 16 + l15] = tv;
      }
    }
  }
#pragma unroll
  for (int m = 1; m < 16; m <<= 1)
#pragma unroll
    for (int q = 0; q < 16; ++q) rs[q] += __shfl_xor(rs[q], m, 64);
  if (l15 == 0) {
    float* rb = rowsum + (size_t)b * L_ + i0 + wm;
#pragma unroll
    for (int ti = 0; ti < 4; ++ti)
#pragma unroll
      for (int r = 0; r < 4; ++r)
        atomicAdd(&rb[ti * 16 + quad * 4 + r], rs[ti * 4 + r]);
  }
}

// ---------------------------------------------------------------------------
// K2: out[c,i] = inv[i] * sum_j Vb[c,j] * t[i,j].  A bf16 async-staged,
// B fp32 cast->bf16 (trunc) during LDS staging.  grid (L/128, C/128, B)
// ---------------------------------------------------------------------------
__global__ __launch_bounds__(256) void gemm2_k(
    const unsigned short* __restrict__ Vb, const float* __restrict__ tmat,
    const float* __restrict__ rowsum, float* __restrict__ out) {
  int b = blockIdx.z;
  int c0 = blockIdx.y * 128;
  int i0 = blockIdx.x * 128;
  __shared__ unsigned short sA[128 * 32];
  __shared__ unsigned short sB[128 * 32];
  const unsigned short* Ab = Vb + (size_t)b * C_ * L_ + (size_t)c0 * L_;
  const float* Bb = tmat + (size_t)b * L_ * L_ + (size_t)i0 * L_;
  int t = threadIdx.x;
  int f0 = t * 8;
  int f1 = 2048 + t * 8;
  int r0 = f0 >> 5, q0 = f0 & 31;
  int r1 = f1 >> 5, q1 = f1 & 31;
  const unsigned short* pA0 = Ab + (size_t)r0 * L_ + q0;
  const unsigned short* pA1 = Ab + (size_t)r1 * L_ + q1;
  const float* pB0 = Bb + (size_t)r0 * L_ + q0;
  const float* pB1 = Bb + (size_t)r1 * L_ + q1;
  int lane = t & 63;
  int quad = lane >> 4;
  int l15 = lane & 15;
  int w = t >> 6;
  int wm = (w & 1) * 64;
  int wn = (w >> 1) * 64;
  f32x4 acc[4][4] = {};
  for (int kk = 0; kk < L_; kk += 32) {
    __syncthreads();
    g2lds16(pA0 + kk, sA + f0);
    g2lds16(pA1 + kk, sA + f1);
    float4 x0 = *(const float4*)(pB0 + kk);
    float4 x1 = *(const float4*)(pB0 + kk + 4);
    float4 y0 = *(const float4*)(pB1 + kk);
    float4 y1 = *(const float4*)(pB1 + kk + 4);
    uint4 u0, u1;
    u0.x = pack_trunc(x0.x, x0.y); u0.y = pack_trunc(x0.z, x0.w);
    u0.z = pack_trunc(x1.x, x1.y); u0.w = pack_trunc(x1.z, x1.w);
    u1.x = pack_trunc(y0.x, y0.y); u1.y = pack_trunc(y0.z, y0.w);
    u1.z = pack_trunc(y1.x, y1.y); u1.w = pack_trunc(y1.z, y1.w);
    *(uint4*)(sB + f0) = u0;
    *(uint4*)(sB + f1) = u1;
    __syncthreads();
    bf16x8 aF[4], bF[4];
#pragma unroll
    for (int ti = 0; ti < 4; ++ti)
      aF[ti] = *(const bf16x8*)(sA + (wm + ti * 16 + l15) * 32 + quad * 8);
#pragma unroll
    for (int tj = 0; tj < 4; ++tj)
      bF[tj] = *(const bf16x8*)(sB + (wn + tj * 16 + l15) * 32 + quad * 8);
#pragma unroll
    for (int ti = 0; ti < 4; ++ti)
#pragma unroll
      for (int tj = 0; tj < 4; ++tj)
        acc[ti][tj] = __builtin_amdgcn_mfma_f32_16x16x32_bf16(
            aF[ti], bF[tj], acc[ti][tj], 0, 0, 0);
  }
  float invv[4];
#pragma unroll
  for (int tj = 0; tj < 4; ++tj)
    invv[tj] = 1.0f / rowsum[(size_t)b * L_ + i0 + wn + tj * 16 + l15];
  float* ob = out + (size_t)b * C_ * L_;
#pragma unroll
  for (int ti = 0; ti < 4; ++ti) {
    int crow = c0 + wm + ti * 16 + quad * 4;
#pragma unroll
    for (int r = 0; r < 4; ++r) {
      size_t ro = (size_t)(crow + r) * L_;
#pragma unroll
      for (int tj = 0; tj < 4; ++tj)
        ob[ro + i0 + wn + tj * 16 + l15] = acc[ti][tj][r] * invv[tj];
    }
  }
}

// ---------------------------------------------------------------------------
// K3: fused in-place transpose + softmax-finalize of each (L,L) fp32 matrix:
// attn <- (t * mask[j] / rowsum[i]) transposed, i.e. reference's
// attention.transpose(0,2,1).  grid (64, 64, B); ti>tj blocks exit.
// Both tiles are drained to LDS before the barrier, so the in-place pair
// swap is race-free (stores happen only after all loads completed).
// ---------------------------------------------------------------------------
__global__ __launch_bounds__(256) void transpose_scale_k(
    float* __restrict__ attn, const float* __restrict__ rowsum,
    const float* __restrict__ mask) {
  int ti = blockIdx.x, tj = blockIdx.y;
  if (ti > tj) return;
  int b = blockIdx.z;
  float* M = attn + (size_t)b * L_ * L_;
  const float* mk = mask + (size_t)b * L_;
  const float* rs = rowsum + (size_t)b * L_;
  __shared__ float t1[64][65];
  __shared__ float t2[64][65];
  int t = threadIdx.x;
  int r = t >> 2, cg = (t & 3) * 16;
  bool diag = (ti == tj);
  {
    const float* xp = M + (size_t)(ti * 64 + r) * L_ + tj * 64 + cg;
    float invx = 1.0f / rs[ti * 64 + r];
    const float* mx = mk + tj * 64 + cg;
#pragma unroll
    for (int q = 0; q < 4; ++q) {
      float4 v = *(const float4*)(xp + 4 * q);
      float4 m = *(const float4*)(mx + 4 * q);
      t1[r][cg + 4 * q + 0] = v.x * m.x * invx;
      t1[r][cg + 4 * q + 1] = v.y * m.y * invx;
      t1[r][cg + 4 * q + 2] = v.z * m.z * invx;
      t1[r][cg + 4 * q + 3] = v.w * m.w * invx;
    }
  }
  if (!diag) {
    const float* yp = M + (size_t)(tj * 64 + r) * L_ + ti * 64 + cg;
    float invy = 1.0f / rs[tj * 64 + r];
    const float* my = mk + ti * 64 + cg;
#pragma unroll
    for (int q = 0; q < 4; ++q) {
      float4 v = *(const float4*)(yp + 4 * q);
      float4 m = *(const float4*)(my + 4 * q);
      t2[r][cg + 4 * q + 0] = v.x * m.x * invy;
      t2[r][cg + 4 * q + 1] = v.y * m.y * invy;
      t2[r][cg + 4 * q + 2] = v.z * m.z * invy;
      t2[r][cg + 4 * q + 3] = v.w * m.w * invy;
    }
  }
  __syncthreads();
  {  // X^T -> block (tj, ti)
    float* dp = M + (size_t)(tj * 64 + r) * L_ + ti * 64 + cg;
#pragma unroll
    for (int q = 0; q < 4; ++q) {
      float4 o;
      o.x = t1[cg + 4 * q + 0][r];
      o.y = t1[cg + 4 * q + 1][r];
      o.z = t1[cg + 4 * q + 2][r];
      o.w = t1[cg + 4 * q + 3][r];
      *(float4*)(dp + 4 * q) = o;
    }
  }
  if (!diag) {  // Y^T -> block (ti, tj)
    float* dp = M + (size_t)(ti * 64 + r) * L_ + tj * 64 + cg;
#pragma unroll
    for (int q = 0; q < 4; ++q) {
      float4 o;
      o.x = t2[cg + 4 * q + 0][r];
      o.y = t2[cg + 4 * q + 1][r];
      o.z = t2[cg + 4 * q + 2][r];
      o.w = t2[cg + 4 * q + 3][r];
      *(float4*)(dp + 4 * q) = o;
    }
  }
}

extern "C" void kernel_launch(void* const* d_in, const int* in_sizes, int n_in,
                              void* d_out, int out_size, void* d_ws,
                              size_t ws_size, hipStream_t stream) {
  const float* Q = (const float*)d_in[0];     // (B,C,L) fp32
  const float* K = (const float*)d_in[1];     // (B,C,L) fp32
  const float* V = (const float*)d_in[2];     // (B,C,L) fp32
  const float* mask = (const float*)d_in[3];  // (B,1,L) fp32

  float* out = (float*)d_out;                       // (B,C,L) fp32
  float* attn = out + (size_t)B_ * C_ * L_;         // (B,L,L) fp32

  unsigned short* Qt = (unsigned short*)d_ws;             // (B,L,C) bf16
  unsigned short* Kt = Qt + (size_t)B_ * L_ * C_;         // (B,L,C) bf16
  unsigned short* Vb = Kt + (size_t)B_ * L_ * C_;         // (B,C,L) bf16
  float* rowsum = (float*)(Vb + (size_t)B_ * C_ * L_);    // (B,L) fp32

  hipMemsetAsync(rowsum, 0, (size_t)B_ * L_ * sizeof(float), stream);

  transpose_cast_k<<<dim3(L_ / 64, C_ / 64, B_ * 2), 256, 0, stream>>>(Q, K, Qt,
                                                                       Kt);
  cast_v_k<<<dim3((B_ * C_ * L_) / 2048), 256, 0, stream>>>(V, mask, Vb);
  gemm1_k<<<dim3(L_ / 128, L_ / 128, B_), 256, 0, stream>>>(Qt, Kt, mask, attn,
                                                            rowsum);
  gemm2_k<<<dim3(L_ / 128, C_ / 128, B_), 256, 0, stream>>>(Vb, attn, rowsum,
                                                            out);
  transpose_scale_k<<<dim3(64, 64, B_), 256, 0, stream>>>(attn, rowsum, mask);
}